// Round 10
// baseline (296.417 us; speedup 1.0000x reference)
//
#include <hip/hip_runtime.h>
#include <stdint.h>
#include <math.h>

// Problem shape (fixed by reference): xs [B,T,N,D] fp32, A [1,N,N] int32
#define BB 4
#define TT 32
#define NN 128
#define DD 32
#define NPB 8                        // nodes per block (8 nodes x 32 d = 256 threads)
#define NBLK (BB * TT * (NN / NPB))  // 2048 blocks = 8/CU = ONE residency generation
#define CAP 16                       // band list capacity; overflow -> exact fallback

// Monotone non-decreasing 8-bin partition (bin0: x<-0.6 incl tail, bin7: x>=0.6
// incl tail, interior width 0.2). Any monotone partition gives exact rank
// selection; selected-bin overflow -> exact fallback. Proven R5-R9 (absmax 0).
__device__ __forceinline__ int bin8(float x) {
    int i = (int)fmaf(x, 5.0f, 4.0f);
    i = i < 0 ? 0 : i;
    return i > 7 ? 7 : i;
}

// Per-node compacted u8 neighbor list + degree (A row + self loop).
__global__ __launch_bounds__(64) void build_adj_kernel(const int* __restrict__ A,
                                                       int* __restrict__ deg,
                                                       uint8_t* __restrict__ nbr) {
    const int n = blockIdx.x;
    const int lane = threadIdx.x;  // 0..63
    const int* arow = A + n * NN;
    uint8_t* row = nbr + n * NN;
    const int j0 = lane, j1 = lane + 64;
    const bool b0 = (arow[j0] != 0) || (j0 == n);
    const bool b1 = (arow[j1] != 0) || (j1 == n);
    const unsigned long long m0 = __ballot(b0);
    const unsigned long long m1 = __ballot(b1);
    const unsigned long long lmask = (1ULL << lane) - 1ULL;
    const int c0 = __popcll(m0);
    if (b0) row[__popcll(m0 & lmask)] = (uint8_t)j0;
    if (b1) row[c0 + __popcll(m1 & lmask)] = (uint8_t)j1;
    if (lane == 0) deg[n] = c0 + __popcll(m1);
}

// R10: NO LDS frame, NO barrier. xs (2 MB) fits each XCD's 4 MB L2; value
// gathers (lanes d=0..31 -> 128 B/node segments) are L1/L2-served with up to
// ~63 outstanding (vmcnt) vs LDS's 15 (lgkmcnt). LDS = slist only (17 KB)
// -> 8 blocks/CU, 32 waves/CU, single generation, zero __syncthreads.
// Selection logic byte-identical to R5 (value histogram -> branchless
// always-store compaction -> streamed counting; exact fallbacks).
// Plain __launch_bounds__(256): R3 proved a waves/EU hint forces spills.
// Census/gmask path retired: R6/R7/R9 all 116-150us vs R5 78us.
__global__ __launch_bounds__(256) void median_kernel(const float* __restrict__ xs,
                                                     const int* __restrict__ deg,
                                                     const uint8_t* __restrict__ nbr,
                                                     float* __restrict__ out) {
    __shared__ float slist[(CAP + 1) * 256];  // 17 KB: band values, column-major
                                              // (bank tid%32, 2-way = free; own-column
                                              // access only -> no barrier ever needed)

    const int tid = threadIdx.x;
    const int g = blockIdx.x;
    const int ng = g % (NN / NPB);
    const int t  = (g / (NN / NPB)) % TT;
    const int b  = g / ((NN / NPB) * TT);
    const int n0 = ng * NPB;
    const int bt = b * TT + t;

    const int d = tid & (DD - 1);
    const int nl = tid >> 5;
    const int n = n0 + nl;
    const int pv = (t > 0) ? 1 : 0;       // wave-uniform
    const int nv = (t < TT - 1) ? 1 : 0;  // wave-uniform

    // per-thread base into current frame: value of node id at this d is xf[id<<5]
    const float* xf = xs + (size_t)bt * NN * DD + d;

    float xprev = 0.0f, xnext = 0.0f;
    if (pv) xprev = xs[(((size_t)(bt - 1) * NN) + n) * DD + d];
    if (nv) xnext = xs[(((size_t)(bt + 1) * NN) + n) * DD + d];

    const int dg = deg[n];                       // L1-broadcast within half-wave
    const uint8_t* gn = nbr + (size_t)n * NN;    // 128 B row, L1-resident
    const int k = dg + pv + nv;
    const uint32_t r = (uint32_t)((k - 1) >> 1);  // lower-median rank (0-based)
    const float INFV = __uint_as_float(0x7F800000u);
    const int tb0 = bin8(xprev), tb1 = bin8(xnext);  // guarded by pv/nv

    // ---- A1: one-pass 8-bin histogram, packed 8x8-bit in u64 (R5-proven) ----
    unsigned long long pcnt = 0ull;
    {
        int j = 0;
        for (; j + 4 <= dg; j += 4) {
            uint32_t nw = *(const uint32_t*)(gn + j);   // wave-broadcast word
            #pragma unroll
            for (int q = 0; q < 4; ++q) {
                float x = xf[(int)((nw >> (q * 8)) & 0xFFu) << 5];
                pcnt += 1ull << (bin8(x) * 8);
            }
        }
        for (; j < dg; ++j) {
            float x = xf[(int)gn[j] << 5];
            pcnt += 1ull << (bin8(x) * 8);
        }
        if (pv) pcnt += 1ull << (tb0 * 8);
        if (nv) pcnt += 1ull << (tb1 * 8);
    }

    // ---- prefix over 8 byte-counts; select bin containing rank r ----
    uint32_t cum = 0, lowcnt = 0, mexp = 0;
    int selbin = -1;
    #pragma unroll
    for (int bb = 0; bb < 8; ++bb) {
        uint32_t bc = (uint32_t)(pcnt >> (bb * 8)) & 0xFFu;
        uint32_t nc = cum + bc;
        if (selbin < 0 && r < nc) { selbin = bb; lowcnt = cum; mexp = bc; }
        cum = nc;
    }
    const bool fb = (mexp > CAP);          // only fallback: band too big
    const uint32_t rp = r - lowcnt;        // rank within band
    const int storebin = fb ? -1 : selbin; // fb lanes store nothing (mc stays 0)

    // ---- A2: branchless always-store compaction into own slist column ----
    int mc = 0;
    {
        int j = 0;
        for (; j + 4 <= dg; j += 4) {
            uint32_t nw = *(const uint32_t*)(gn + j);
            #pragma unroll
            for (int q = 0; q < 4; ++q) {
                float x = xf[(int)((nw >> (q * 8)) & 0xFFu) << 5];
                int slot = mc > CAP ? CAP : mc;
                slist[slot * 256 + tid] = x;
                mc += (bin8(x) == storebin);
            }
        }
        for (; j < dg; ++j) {
            float x = xf[(int)gn[j] << 5];
            int slot = mc > CAP ? CAP : mc;
            slist[slot * 256 + tid] = x;
            mc += (bin8(x) == storebin);
        }
        if (pv) {
            int slot = mc > CAP ? CAP : mc;
            slist[slot * 256 + tid] = xprev;
            mc += (tb0 == storebin);
        }
        if (nv) {
            int slot = mc > CAP ? CAP : mc;
            slist[slot * 256 + tid] = xnext;
            mc += (tb1 == storebin);
        }
    }

    // ---- phase B: streamed counting selection (R5-proven register shape) ----
    float ki[CAP];
    uint32_t cn[CAP];
    #pragma unroll
    for (int u = 0; u < CAP; ++u) {
        float v = slist[u * 256 + tid];
        ki[u] = (u < mc) ? v : INFV;
        cn[u] = 0;
    }
    int mm = mc;  // wave max -> uniform trip count
    #pragma unroll
    for (int off = 32; off; off >>= 1) {
        int o = __shfl_xor(mm, off);
        mm = mm > o ? mm : o;
    }
    for (int j = 0; j < mm; ++j) {
        float x = slist[j * 256 + tid];
        x = (j < mc) ? x : INFV;
        #pragma unroll
        for (int u = 0; u < CAP; ++u) cn[u] += (x < ki[u]);
    }
    float result = 0.0f;
    bool found = fb;
    #pragma unroll
    for (int u = 0; u < CAP; ++u) {
        // strict-below count == rp identifies rank-rp exactly (unique per value)
        if (!found && u < mc && cn[u] == rp) { result = ki[u]; found = true; }
    }

    // ---- duplicate-median pass (exact multiset lower-median; ~never runs) ----
    if (__ballot(!found)) {
        uint32_t eq[CAP];
        #pragma unroll
        for (int u = 0; u < CAP; ++u) eq[u] = 0;
        for (int j = 0; j < mm; ++j) {
            float x = slist[j * 256 + tid];
            x = (j < mc) ? x : INFV;
            #pragma unroll
            for (int u = 0; u < CAP; ++u) eq[u] += (x == ki[u]);
        }
        #pragma unroll
        for (int u = 0; u < CAP; ++u) {
            if (!found && u < mc && cn[u] <= rp && rp < cn[u] + eq[u]) {
                result = ki[u]; found = true;
            }
        }
    }

    // ---- full fallback (band > CAP; ~1e-6/lane): exact scan over all k ----
    if (__ballot(fb)) {
        bool done = !fb;
        for (int i0 = 0; __ballot(!done) && i0 < 132; i0 += 4) {
            if (!done) {
                float k4[4]; uint32_t lt4[4], le4[4];
                #pragma unroll
                for (int u = 0; u < 4; ++u) {
                    int i = i0 + u;
                    float v;
                    if (i < dg) v = xf[(int)gn[i] << 5];
                    else if (i == dg && pv) v = xprev;
                    else if (i == dg + pv && i < k) v = xnext;
                    else v = INFV;
                    k4[u] = (i < k) ? v : INFV;
                    lt4[u] = 0; le4[u] = 0;
                }
                for (int j = 0; j < dg; ++j) {
                    float xv = xf[(int)gn[j] << 5];
                    #pragma unroll
                    for (int u = 0; u < 4; ++u) { lt4[u] += (xv < k4[u]); le4[u] += (xv <= k4[u]); }
                }
                if (pv) {
                    #pragma unroll
                    for (int u = 0; u < 4; ++u) { lt4[u] += (xprev < k4[u]); le4[u] += (xprev <= k4[u]); }
                }
                if (nv) {
                    #pragma unroll
                    for (int u = 0; u < 4; ++u) { lt4[u] += (xnext < k4[u]); le4[u] += (xnext <= k4[u]); }
                }
                #pragma unroll
                for (int u = 0; u < 4; ++u) {
                    if (!done && (i0 + u) < k && lt4[u] <= r && r < le4[u]) {
                        result = k4[u]; done = true;
                    }
                }
            }
        }
    }

    out[(((size_t)bt * NN) + n) * DD + d] = result;
}

extern "C" void kernel_launch(void* const* d_in, const int* in_sizes, int n_in,
                              void* d_out, int out_size, void* d_ws, size_t ws_size,
                              hipStream_t stream) {
    const float* xs = (const float*)d_in[0];
    const int* A = (const int*)d_in[1];
    float* out = (float*)d_out;

    // workspace: deg int[128] (512 B) | nbr u8[128*128] (16 KB)
    int* deg = (int*)d_ws;
    uint8_t* nbr = (uint8_t*)d_ws + 512;

    build_adj_kernel<<<NN, 64, 0, stream>>>(A, deg, nbr);
    median_kernel<<<NBLK, 256, 0, stream>>>(xs, deg, nbr, out);
}

// Round 11
// 249.748 us; speedup vs baseline: 1.1869x; 1.1869x over previous
//
#include <hip/hip_runtime.h>
#include <stdint.h>
#include <math.h>

// Problem shape (fixed by reference): xs [B,T,N,D] fp32, A [1,N,N] int32
#define BB 4
#define TT 32
#define NN 128
#define DD 32
#define NPB 32                       // nodes per block (32 nodes x 32 d = 1024 threads)
#define NTH 1024
#define NBLK (BB * TT * (NN / NPB))  // 512 blocks = exactly 2/CU
#define SLOTS 15                     // slist columns (60 KB); band > MAXM -> exact fallback
#define MAXM 14

// Monotone non-decreasing 8-bin partition (bin0: x<-0.6 incl tail, bin7: x>=0.6
// incl tail, interior width 0.2). Any monotone partition gives exact rank
// selection; selected-bin overflow -> exact fallback. Proven R5-R10 (absmax 0).
__device__ __forceinline__ int bin8(float x) {
    int i = (int)fmaf(x, 5.0f, 4.0f);
    i = i < 0 ? 0 : i;
    return i > 7 ? 7 : i;
}

// Per-node compacted u8 neighbor list + degree (A row + self loop).
__global__ __launch_bounds__(64) void build_adj_kernel(const int* __restrict__ A,
                                                       int* __restrict__ deg,
                                                       uint8_t* __restrict__ nbr) {
    const int n = blockIdx.x;
    const int lane = threadIdx.x;  // 0..63
    const int* arow = A + n * NN;
    uint8_t* row = nbr + n * NN;
    const int j0 = lane, j1 = lane + 64;
    const bool b0 = (arow[j0] != 0) || (j0 == n);
    const bool b1 = (arow[j1] != 0) || (j1 == n);
    const unsigned long long m0 = __ballot(b0);
    const unsigned long long m1 = __ballot(b1);
    const unsigned long long lmask = (1ULL << lane) - 1ULL;
    const int c0 = __popcll(m0);
    if (b0) row[__popcll(m0 & lmask)] = (uint8_t)j0;
    if (b1) row[c0 + __popcll(m1 & lmask)] = (uint8_t)j1;
    if (lane == 0) deg[n] = c0 + __popcll(m1);
}

// R11 = R5's exact selection algorithm (78us champion) at 2x residency.
// 1024-thread blocks: ONE 16 KB sval copy serves 4x the outputs; slist 15
// columns (60 KB); neighbor words + deg from global (wave-uniform 128 B rows,
// L1-served; R10 proved these loads are cheap at 52 VGPR -- only the VALUE
// gathers from L2 were toxic). LDS 76 KB -> 2 blocks/CU = 32 waves/CU (HW max)
// vs R5's 16. Plain __launch_bounds__ (R3: waves-hint => scratch spills).
// Retired by measurement: census/gmask (R6/7/9), L2-direct values (R10),
// register phase-B (R6), ffs bit-walk (R6/7).
__global__ __launch_bounds__(NTH) void median_kernel(const float* __restrict__ xs,
                                                     const int* __restrict__ deg,
                                                     const uint8_t* __restrict__ nbr,
                                                     float* __restrict__ out) {
    __shared__ float sval[NN * DD];        // 16 KB: frame, stride 32 (value reads bank=d)
    __shared__ float slist[SLOTS * NTH];   // 60 KB: band values, column-major (bank tid%32)

    const int tid = threadIdx.x;
    const int g = blockIdx.x;
    const int ng = g % (NN / NPB);
    const int t  = (g / (NN / NPB)) % TT;
    const int b  = g / ((NN / NPB) * TT);
    const int n0 = ng * NPB;
    const int bt = b * TT + t;

    const int d = tid & (DD - 1);
    const int nl = tid >> 5;              // local node 0..31
    const int n = n0 + nl;
    const int pv = (t > 0) ? 1 : 0;       // wave-uniform
    const int nv = (t < TT - 1) ? 1 : 0;  // wave-uniform

    float xprev = 0.0f, xnext = 0.0f;
    if (pv) xprev = xs[(((size_t)(bt - 1) * NN) + n) * DD + d];
    if (nv) xnext = xs[(((size_t)(bt + 1) * NN) + n) * DD + d];

    const int dg = deg[n];                     // L1-broadcast
    const uint8_t* gn = nbr + (size_t)n * NN;  // 128 B row, L1-resident

    // stage frame: exactly one float4 per thread
    ((float4*)sval)[tid] = ((const float4*)(xs + (size_t)bt * NN * DD))[tid];
    __syncthreads();

    const int k = dg + pv + nv;
    const uint32_t r = (uint32_t)((k - 1) >> 1);  // lower-median rank (0-based)
    const float INFV = __uint_as_float(0x7F800000u);
    const int tb0 = bin8(xprev), tb1 = bin8(xnext);  // guarded by pv/nv

    // ---- A1: one-pass 8-bin histogram, packed 8x8-bit in u64 (R5-proven) ----
    unsigned long long pcnt = 0ull;
    {
        int j = 0;
        for (; j + 4 <= dg; j += 4) {
            uint32_t nw = *(const uint32_t*)(gn + j);   // wave-uniform global word
            #pragma unroll
            for (int q = 0; q < 4; ++q) {
                float x = sval[((nw >> (q * 8)) & 0xFFu) * DD + d];
                pcnt += 1ull << (bin8(x) * 8);
            }
        }
        for (; j < dg; ++j) {
            float x = sval[(int)gn[j] * DD + d];
            pcnt += 1ull << (bin8(x) * 8);
        }
        if (pv) pcnt += 1ull << (tb0 * 8);
        if (nv) pcnt += 1ull << (tb1 * 8);
    }

    // ---- prefix over 8 byte-counts; select bin containing rank r ----
    uint32_t cum = 0, lowcnt = 0, mexp = 0;
    int selbin = -1;
    #pragma unroll
    for (int bb = 0; bb < 8; ++bb) {
        uint32_t bc = (uint32_t)(pcnt >> (bb * 8)) & 0xFFu;
        uint32_t nc = cum + bc;
        if (selbin < 0 && r < nc) { selbin = bb; lowcnt = cum; mexp = bc; }
        cum = nc;
    }
    const bool fb = (mexp > MAXM);         // only fallback: band too big
    const uint32_t rp = r - lowcnt;        // rank within band
    const int storebin = fb ? -1 : selbin; // fb lanes store nothing (mc stays 0)

    // ---- A2: branchless always-store compaction into own slist column ----
    // Non-members overwrite slot min(mc, SLOTS-1); members (mc<=MAXM) each get a
    // distinct slot 0..MAXM-? and are the LAST write to that slot. Slot SLOTS-1
    // is scratch only when mc==MAXM+? (never read beyond mc).
    int mc = 0;
    {
        int j = 0;
        for (; j + 4 <= dg; j += 4) {
            uint32_t nw = *(const uint32_t*)(gn + j);
            #pragma unroll
            for (int q = 0; q < 4; ++q) {
                float x = sval[((nw >> (q * 8)) & 0xFFu) * DD + d];
                int slot = mc > SLOTS - 1 ? SLOTS - 1 : mc;
                slist[slot * NTH + tid] = x;
                mc += (bin8(x) == storebin);
            }
        }
        for (; j < dg; ++j) {
            float x = sval[(int)gn[j] * DD + d];
            int slot = mc > SLOTS - 1 ? SLOTS - 1 : mc;
            slist[slot * NTH + tid] = x;
            mc += (bin8(x) == storebin);
        }
        if (pv) {
            int slot = mc > SLOTS - 1 ? SLOTS - 1 : mc;
            slist[slot * NTH + tid] = xprev;
            mc += (tb0 == storebin);
        }
        if (nv) {
            int slot = mc > SLOTS - 1 ? SLOTS - 1 : mc;
            slist[slot * NTH + tid] = xnext;
            mc += (tb1 == storebin);
        }
    }

    // ---- phase B: streamed counting selection (R5-proven register shape) ----
    float ki[SLOTS];
    uint32_t cn[SLOTS];
    #pragma unroll
    for (int u = 0; u < SLOTS; ++u) {
        float v = slist[u * NTH + tid];
        ki[u] = (u < mc) ? v : INFV;
        cn[u] = 0;
    }
    int mm = mc;  // wave max -> uniform trip count
    #pragma unroll
    for (int off = 32; off; off >>= 1) {
        int o = __shfl_xor(mm, off);
        mm = mm > o ? mm : o;
    }
    for (int j = 0; j < mm; ++j) {
        float x = slist[j * NTH + tid];
        x = (j < mc) ? x : INFV;
        #pragma unroll
        for (int u = 0; u < SLOTS; ++u) cn[u] += (x < ki[u]);
    }
    float result = 0.0f;
    bool found = fb;
    #pragma unroll
    for (int u = 0; u < SLOTS; ++u) {
        // strict-below count == rp identifies rank-rp exactly (unique per value)
        if (!found && u < mc && cn[u] == rp) { result = ki[u]; found = true; }
    }

    // ---- duplicate-median pass (exact multiset lower-median; ~never runs) ----
    if (__ballot(!found)) {
        uint32_t eq[SLOTS];
        #pragma unroll
        for (int u = 0; u < SLOTS; ++u) eq[u] = 0;
        for (int j = 0; j < mm; ++j) {
            float x = slist[j * NTH + tid];
            x = (j < mc) ? x : INFV;
            #pragma unroll
            for (int u = 0; u < SLOTS; ++u) eq[u] += (x == ki[u]);
        }
        #pragma unroll
        for (int u = 0; u < SLOTS; ++u) {
            if (!found && u < mc && cn[u] <= rp && rp < cn[u] + eq[u]) {
                result = ki[u]; found = true;
            }
        }
    }

    // ---- full fallback (band > MAXM; ~2e-5/lane): exact scan over all k ----
    if (__ballot(fb)) {
        bool done = !fb;
        for (int i0 = 0; __ballot(!done) && i0 < 132; i0 += 4) {
            if (!done) {
                float k4[4]; uint32_t lt4[4], le4[4];
                #pragma unroll
                for (int u = 0; u < 4; ++u) {
                    int i = i0 + u;
                    float v;
                    if (i < dg) v = sval[(int)gn[i] * DD + d];
                    else if (i == dg && pv) v = xprev;
                    else if (i == dg + pv && i < k) v = xnext;
                    else v = INFV;
                    k4[u] = (i < k) ? v : INFV;
                    lt4[u] = 0; le4[u] = 0;
                }
                for (int j = 0; j < dg; ++j) {
                    float xv = sval[(int)gn[j] * DD + d];
                    #pragma unroll
                    for (int u = 0; u < 4; ++u) { lt4[u] += (xv < k4[u]); le4[u] += (xv <= k4[u]); }
                }
                if (pv) {
                    #pragma unroll
                    for (int u = 0; u < 4; ++u) { lt4[u] += (xprev < k4[u]); le4[u] += (xprev <= k4[u]); }
                }
                if (nv) {
                    #pragma unroll
                    for (int u = 0; u < 4; ++u) { lt4[u] += (xnext < k4[u]); le4[u] += (xnext <= k4[u]); }
                }
                #pragma unroll
                for (int u = 0; u < 4; ++u) {
                    if (!done && (i0 + u) < k && lt4[u] <= r && r < le4[u]) {
                        result = k4[u]; done = true;
                    }
                }
            }
        }
    }

    out[(((size_t)bt * NN) + n) * DD + d] = result;
}

extern "C" void kernel_launch(void* const* d_in, const int* in_sizes, int n_in,
                              void* d_out, int out_size, void* d_ws, size_t ws_size,
                              hipStream_t stream) {
    const float* xs = (const float*)d_in[0];
    const int* A = (const int*)d_in[1];
    float* out = (float*)d_out;

    // workspace: deg int[128] (512 B) | nbr u8[128*128] (16 KB)
    int* deg = (int*)d_ws;
    uint8_t* nbr = (uint8_t*)d_ws + 512;

    build_adj_kernel<<<NN, 64, 0, stream>>>(A, deg, nbr);
    median_kernel<<<NBLK, NTH, 0, stream>>>(xs, deg, nbr, out);
}